// Round 6
// baseline (463.550 us; speedup 1.0000x reference)
//
#include <hip/hip_runtime.h>
#include <math.h>

#define TS 60            // LDS tile stride: 32 rows x 60 cols
#define FINF 3.4e38f

__device__ __forceinline__ int iclip(int v, int hi) {
  return v < 0 ? 0 : (v > hi ? hi : v);
}

// Exact f32 values of the reference D8 (computed in f64, cast to f32).
constexpr float CA = 0.35355339059327373f;
constexpr float K1 = 0.49039264020161522f;
constexpr float K2 = 0.46193976625564337f;
constexpr float K3 = 0.41573480615127262f;
constexpr float K4 = 0.35355339059327379f;
constexpr float K5 = 0.27778511650980111f;
constexpr float K6 = 0.19134171618254489f;
constexpr float K7 = 0.097545161008064135f;

constexpr float DCT8[8][8] = {
  { CA, CA, CA, CA, CA, CA, CA, CA},
  { K1, K3, K5, K7,-K7,-K5,-K3,-K1},
  { K2, K6,-K6,-K2,-K2,-K6, K6, K2},
  { K3,-K7,-K1,-K5, K5, K1, K7,-K3},
  { K4,-K4,-K4, K4, K4,-K4,-K4, K4},
  { K5,-K1, K7, K3,-K3,-K7, K1,-K5},
  { K6,-K2, K2,-K6,-K6, K2,-K2, K6},
  { K7,-K5, K3,-K1, K1,-K3, K5,-K7},
};

// lane-xor exchange: DPP for 1/2, ds_swizzle for 4/8/16, shfl for 32
__device__ __forceinline__ int sxor_i(int v, int m) {
  switch (m) {
    case 1:  return __builtin_amdgcn_update_dpp(0, v, 0xB1, 0xF, 0xF, true);
    case 2:  return __builtin_amdgcn_update_dpp(0, v, 0x4E, 0xF, 0xF, true);
    case 4:  return __builtin_amdgcn_ds_swizzle(v, (4 << 10) | 0x1F);
    case 8:  return __builtin_amdgcn_ds_swizzle(v, (8 << 10) | 0x1F);
    case 16: return __builtin_amdgcn_ds_swizzle(v, (16 << 10) | 0x1F);
    default: return __shfl_xor(v, 32, 64);
  }
}
__device__ __forceinline__ float sxor_f(float v, int m) {
  return __int_as_float(sxor_i(__float_as_int(v), m));
}

// broadcast from quad lane s (VALU DPP)
__device__ __forceinline__ float qbcast(float v, int s) {
  int x = __float_as_int(v), r;
  switch (s) {
    case 0:  r = __builtin_amdgcn_update_dpp(0, x, 0x00, 0xF, 0xF, true); break;
    case 1:  r = __builtin_amdgcn_update_dpp(0, x, 0x55, 0xF, 0xF, true); break;
    case 2:  r = __builtin_amdgcn_update_dpp(0, x, 0xAA, 0xF, 0xF, true); break;
    default: r = __builtin_amdgcn_update_dpp(0, x, 0xFF, 0xF, 0xF, true); break;
  }
  return __int_as_float(r);
}

// forward: row DCT (lane-local literals) then column DCT (quad mix)
__device__ __forceinline__ void fwd_rowcol(float X[2][8], float U[2][8],
                                           const float Ca0[8], const float Ca1[8]) {
#pragma unroll
  for (int r = 0; r < 2; r++)
#pragma unroll
    for (int d = 0; d < 8; d++) {
      float s = X[r][0] * DCT8[d][0];
#pragma unroll
      for (int c = 1; c < 8; c++) s += X[r][c] * DCT8[d][c];
      U[r][d] = s;
    }
#pragma unroll
  for (int r = 0; r < 2; r++)
#pragma unroll
    for (int d = 0; d < 8; d++) X[r][d] = 0.f;
#pragma unroll
  for (int b = 0; b < 8; b++)
#pragma unroll
    for (int d = 0; d < 8; d++) {
      float yb = qbcast(U[b & 1][d], b >> 1);
      X[0][d] += Ca0[b] * yb;
      X[1][d] += Ca1[b] * yb;
    }
}

// inverse: column (quad mix, D^T coeffs) then row (lane-local literals)
__device__ __forceinline__ void inv_colrow(float X[2][8], float U[2][8],
                                           const float Ct0[8], const float Ct1[8]) {
#pragma unroll
  for (int r = 0; r < 2; r++)
#pragma unroll
    for (int d = 0; d < 8; d++) U[r][d] = 0.f;
#pragma unroll
  for (int a = 0; a < 8; a++)
#pragma unroll
    for (int d = 0; d < 8; d++) {
      float za = qbcast(X[a & 1][d], a >> 1);
      U[0][d] += Ct0[a] * za;
      U[1][d] += Ct1[a] * za;
    }
#pragma unroll
  for (int r = 0; r < 2; r++)
#pragma unroll
    for (int c = 0; c < 8; c++) {
      float s = U[r][0] * DCT8[0][c];
#pragma unroll
      for (int d = 1; d < 8; d++) s += U[r][d] * DCT8[d][c];
      X[r][c] = s;
    }
}

// fused 2-group 16-point Walsh-Hadamard across lane bits 2..5, scale 1/4
__device__ __forceinline__ void had16r2(float X0[2][8], float X1[2][8], int lane) {
#pragma unroll
  for (int m = 4; m <= 32; m <<= 1) {
    bool hi = (lane & m) != 0;
#pragma unroll
    for (int r = 0; r < 2; r++)
#pragma unroll
      for (int d = 0; d < 8; d++) {
        float t0 = sxor_f(X0[r][d], m);
        float t1 = sxor_f(X1[r][d], m);
        X0[r][d] = hi ? (t0 - X0[r][d]) : (X0[r][d] + t0);
        X1[r][d] = hi ? (t1 - X1[r][d]) : (X1[r][d] + t1);
      }
  }
#pragma unroll
  for (int r = 0; r < 2; r++)
#pragma unroll
    for (int d = 0; d < 8; d++) { X0[r][d] *= 0.25f; X1[r][d] *= 0.25f; }
}

template <int WIEN>
__global__ __launch_bounds__(256, 4) void bm3d_pass(
    const int* __restrict__ img, const float* __restrict__ basic,
    const int* __restrict__ pvar,
    float* __restrict__ num, float* __restrict__ den) {
  __shared__ float ldsD[64], ldsDT[64];
  __shared__ __align__(16) float wdist[8][84];
  __shared__ int wsel[8][16];
  __shared__ float bufA[32 * TS];  // step1: tileN -> accN | step2: tileB -> accN
  __shared__ float bufB[32 * TS];  // step1: ......-> accD | step2: tileN -> accD

  int t = threadIdx.x;
  int brow = blockIdx.x / 12, bcb = blockIdx.x - brow * 12;
  int ri = brow * 4;
  int bim = ri - 12;       int bi = bim < 0 ? 0 : (bim > 352 ? 352 : bim);
  int ubm = 32 * bcb - 12; int ub = ubm < 0 ? 0 : (ubm > 324 ? 324 : ubm);

  if (t < 64) ldsD[t] = DCT8[t >> 3][t & 7];
  else if (t < 128) { int u = t - 64; ldsDT[u] = DCT8[u & 7][u >> 3]; }

  // tile load: 480 float4/int4 rows-of-15, always in range
  for (int e4 = t; e4 < 480; e4 += 256) {
    int r = e4 / 15, c4 = (e4 - r * 15) << 2;
    int gidx = (bi + r) * 384 + ub + c4;
    int o = r * TS + c4;
    int4 iv = *(const int4*)&img[gidx];
    float4 fv = make_float4((float)iv.x, (float)iv.y, (float)iv.z, (float)iv.w);
    if (WIEN) {
      *(float4*)&bufA[o] = *(const float4*)&basic[gidx];
      *(float4*)&bufB[o] = fv;
    } else {
      *(float4*)&bufA[o] = fv;
    }
  }
  __syncthreads();

  float sigma2 = (float)pvar[0];
  int wv = t >> 6, lane = t & 63;
  int s0 = 2 * wv, s1 = 2 * wv + 1;
  int g0 = bcb * 8 + 2 * wv, g1 = g0 + 1;
  bool active0 = g0 < 95, active1 = g1 < 95;
  int rj0 = (active0 ? g0 : 94) * 4;
  int rj1 = (active1 ? g1 : 94) * 4;

  const float* tileS = bufA;                 // match source (basic in step2)
  const float* tileN = WIEN ? bufB : bufA;   // noisy pixels

  // ---------- block match: 2 groups x (candidate lane, candidate 64+lane) ----
  int cB = lane < 17 ? 64 + lane : 80;
  int oiA = (lane / 9) * 3 - 12, ojA = (lane % 9) * 3 - 12;
  int oiB = (cB / 9) * 3 - 12,   ojB = (cB % 9) * 3 - 12;
  int aiA = iclip(ri + oiA, 376) - bi;
  int aiB = iclip(ri + oiB, 376) - bi;
  int ajA0 = iclip(rj0 + ojA, 376) - ub, ajA1 = iclip(rj1 + ojA, 376) - ub;
  int ajB0 = iclip(rj0 + ojB, 376) - ub, ajB1 = iclip(rj1 + ojB, 376) - ub;
  int roi = ri - bi, roj0 = rj0 - ub, roj1 = rj1 - ub;

  float sA0c = 0.f, sA0r = 0.f, sB0c = 0.f, sB0r = 0.f;
  float sA1c = 0.f, sA1r = 0.f, sB1c = 0.f, sB1r = 0.f;
  float srr0 = 0.f, srr1 = 0.f;
#pragma unroll
  for (int i = 0; i < 8; i++) {
    const float* r0p = tileS + (roi + i) * TS + roj0;
    const float* r1p = tileS + (roi + i) * TS + roj1;
    const float* a0p = tileS + (aiA + i) * TS + ajA0;
    const float* a1p = tileS + (aiA + i) * TS + ajA1;
    const float* b0p = tileS + (aiB + i) * TS + ajB0;
    const float* b1p = tileS + (aiB + i) * TS + ajB1;
#pragma unroll
    for (int j = 0; j < 8; j++) {
      float rv0 = r0p[j], rv1 = r1p[j];
      float a0 = a0p[j], a1 = a1p[j], b0 = b0p[j], b1 = b1p[j];
      sA0c += a0 * a0; sA0r += a0 * rv0;
      sA1c += a1 * a1; sA1r += a1 * rv1;
      sB0c += b0 * b0; sB0r += b0 * rv0;
      sB1c += b1 * b1; sB1r += b1 * rv1;
      srr0 += rv0 * rv0; srr1 += rv1 * rv1;
    }
  }
  float dA0 = sA0c - 2.f * sA0r + srr0;
  float dA1 = sA1c - 2.f * sA1r + srr1;
  float dB0 = lane < 17 ? (sB0c - 2.f * sB0r + srr0) : FINF;
  float dB1 = lane < 17 ? (sB1c - 2.f * sB1r + srr1) : FINF;

  // wave-local distance tables (no block barrier needed: same-wave LDS RAW)
  wdist[s0][lane] = dA0;
  wdist[s1][lane] = dA1;
  if (lane < 17)      { wdist[s0][64 + lane] = dB0; wdist[s1][64 + lane] = dB1; }
  else if (lane < 20) { wdist[s0][64 + lane] = FINF; wdist[s1][64 + lane] = FINF; }

  // ---------- rank-count top-16 (lexicographic (d, idx) = lax.top_k order) ----
  int rA0 = 0, rB0 = 0, rA1 = 0, rB1 = 0;
  const float4* wp0 = (const float4*)&wdist[s0][0];
  const float4* wp1 = (const float4*)&wdist[s1][0];
  int idxA = lane, idxB = 64 + lane;
#pragma unroll 3
  for (int c4 = 0; c4 < 21; c4++) {
    float4 v0 = wp0[c4], v1 = wp1[c4];
    float e0[4] = {v0.x, v0.y, v0.z, v0.w};
    float e1[4] = {v1.x, v1.y, v1.z, v1.w};
#pragma unroll
    for (int u = 0; u < 4; u++) {
      int c2 = c4 * 4 + u;
      rA0 += (e0[u] < dA0 || (e0[u] == dA0 && c2 < idxA)) ? 1 : 0;
      rB0 += (e0[u] < dB0 || (e0[u] == dB0 && c2 < idxB)) ? 1 : 0;
      rA1 += (e1[u] < dA1 || (e1[u] == dA1 && c2 < idxA)) ? 1 : 0;
      rB1 += (e1[u] < dB1 || (e1[u] == dB1 && c2 < idxB)) ? 1 : 0;
    }
  }
  if (rA0 < 16) wsel[s0][rA0] = (aiA << 8) | ajA0;
  if (rA1 < 16) wsel[s1][rA1] = (aiA << 8) | ajA1;
  if (lane < 17) {
    if (rB0 < 16) wsel[s0][rB0] = (aiB << 8) | ajB0;
    if (rB1 < 16) wsel[s1][rB1] = (aiB << 8) | ajB1;
  }

  // ---------- per-lane geometry + coefficients (float4 loads) ----------
  int k = lane >> 2, q = lane & 3;
  int sp0 = wsel[s0][k], sp1 = wsel[s1][k];
  int gi0 = (sp0 >> 8) + 2 * q, gj0 = sp0 & 255;
  int gi1 = (sp1 >> 8) + 2 * q, gj1 = sp1 & 255;

  float Ca0[8], Ca1[8];
  *(float4*)&Ca0[0] = *(const float4*)&ldsD[(2 * q) * 8];
  *(float4*)&Ca0[4] = *(const float4*)&ldsD[(2 * q) * 8 + 4];
  *(float4*)&Ca1[0] = *(const float4*)&ldsD[(2 * q + 1) * 8];
  *(float4*)&Ca1[4] = *(const float4*)&ldsD[(2 * q + 1) * 8 + 4];

  float X0[2][8], X1[2][8], U[2][8];
  float w0, w1;

  if (WIEN) {
    float Z0[2][8], Z1[2][8];
#pragma unroll
    for (int r = 0; r < 2; r++)
#pragma unroll
      for (int c = 0; c < 8; c++) {
        Z0[r][c] = tileS[(gi0 + r) * TS + gj0 + c];
        Z1[r][c] = tileS[(gi1 + r) * TS + gj1 + c];
      }
    fwd_rowcol(Z0, U, Ca0, Ca1);
    fwd_rowcol(Z1, U, Ca0, Ca1);
    had16r2(Z0, Z1, lane);                       // cb for both groups

#pragma unroll
    for (int r = 0; r < 2; r++)
#pragma unroll
      for (int c = 0; c < 8; c++) {
        X0[r][c] = tileN[(gi0 + r) * TS + gj0 + c];
        X1[r][c] = tileN[(gi1 + r) * TS + gj1 + c];
      }
    fwd_rowcol(X0, U, Ca0, Ca1);
    fwd_rowcol(X1, U, Ca0, Ca1);
    had16r2(X0, X1, lane);                       // cn for both groups

    float p0 = 0.f, p1 = 0.f;
#pragma unroll
    for (int r = 0; r < 2; r++)
#pragma unroll
      for (int d = 0; d < 8; d++) {
        float cb0 = Z0[r][d], cb1 = Z1[r][d];
        float we0 = cb0 * cb0 / (cb0 * cb0 + sigma2);
        float we1 = cb1 * cb1 / (cb1 * cb1 + sigma2);
        X0[r][d] = we0 * X0[r][d];
        X1[r][d] = we1 * X1[r][d];
        p0 += we0 * we0; p1 += we1 * we1;
      }
#pragma unroll
    for (int m = 1; m <= 32; m <<= 1) { p0 += sxor_f(p0, m); p1 += sxor_f(p1, m); }
    w0 = 1.f / (sigma2 * fmaxf(p0, 1e-8f));
    w1 = 1.f / (sigma2 * fmaxf(p1, 1e-8f));
  } else {
#pragma unroll
    for (int r = 0; r < 2; r++)
#pragma unroll
      for (int c = 0; c < 8; c++) {
        X0[r][c] = tileN[(gi0 + r) * TS + gj0 + c];
        X1[r][c] = tileN[(gi1 + r) * TS + gj1 + c];
      }
    fwd_rowcol(X0, U, Ca0, Ca1);
    fwd_rowcol(X1, U, Ca0, Ca1);
    had16r2(X0, X1, lane);

    float thr = 2.7f * sqrtf(sigma2);
    int cnt0 = 0, cnt1 = 0;
#pragma unroll
    for (int r = 0; r < 2; r++)
#pragma unroll
      for (int d = 0; d < 8; d++) {
        bool dc = (lane == 0 && r == 0 && d == 0);
        bool k0 = (fabsf(X0[r][d]) > thr) || dc;
        bool k1 = (fabsf(X1[r][d]) > thr) || dc;
        cnt0 += (int)__popcll(__ballot(k0));
        cnt1 += (int)__popcll(__ballot(k1));
        if (!k0) X0[r][d] = 0.f;
        if (!k1) X1[r][d] = 0.f;
      }
    w0 = 1.f / (sigma2 * fmaxf((float)cnt0, 1.f));
    w1 = 1.f / (sigma2 * fmaxf((float)cnt1, 1.f));
  }

  had16r2(X0, X1, lane);
#pragma unroll
  for (int a = 0; a < 8; a++) {        // D^T rows for this lane's two b's
    Ca0[a] = ldsDT[(2 * q) * 8 + a];
    Ca1[a] = ldsDT[(2 * q + 1) * 8 + a];
  }
  inv_colrow(X0, U, Ca0, Ca1);
  inv_colrow(X1, U, Ca0, Ca1);

  // ---------- overlay: tiles dead, reuse as num/den accumulators ----------
  __syncthreads();
  for (int e = t; e < 32 * TS; e += 256) { bufA[e] = 0.f; bufB[e] = 0.f; }
  __syncthreads();

  if (active0) {
#pragma unroll
    for (int r = 0; r < 2; r++)
#pragma unroll
      for (int c = 0; c < 8; c++) {
        int off = (gi0 + r) * TS + gj0 + c;
        atomicAdd(&bufA[off], w0 * X0[r][c]);
        atomicAdd(&bufB[off], w0);
      }
  }
  if (active1) {
#pragma unroll
    for (int r = 0; r < 2; r++)
#pragma unroll
      for (int c = 0; c < 8; c++) {
        int off = (gi1 + r) * TS + gj1 + c;
        atomicAdd(&bufA[off], w1 * X1[r][c]);
        atomicAdd(&bufB[off], w1);
      }
  }
  __syncthreads();

  for (int e = t; e < 32 * TS; e += 256) {
    float dv = bufB[e];
    if (dv != 0.f) {
      int r = e / TS, c = e - r * TS;
      int gp = (bi + r) * 384 + ub + c;
      atomicAdd(&num[gp], bufA[e]);
      atomicAdd(&den[gp], dv);
    }
  }
}

__global__ void div_kernel(const float* __restrict__ num,
                           const float* __restrict__ den,
                           float* __restrict__ out, int npix) {
  int i = blockIdx.x * blockDim.x + threadIdx.x;
  if (i < npix) out[i] = num[i] / fmaxf(den[i], 1e-8f);
}

extern "C" void kernel_launch(void* const* d_in, const int* in_sizes, int n_in,
                              void* d_out, int out_size, void* d_ws, size_t ws_size,
                              hipStream_t stream) {
  const int* img  = (const int*)d_in[0];
  const int* pvar = (const int*)d_in[1];
  float* out = (float*)d_out;
  float* ws  = (float*)d_ws;

  const int NPIX = 384 * 384;
  float* num1  = ws + 0 * NPIX;
  float* den1  = ws + 1 * NPIX;
  float* basic = ws + 2 * NPIX;
  float* num2  = ws + 3 * NPIX;
  float* den2  = ws + 4 * NPIX;

  hipMemsetAsync(num1, 0, (size_t)2 * NPIX * sizeof(float), stream);
  hipMemsetAsync(num2, 0, (size_t)2 * NPIX * sizeof(float), stream);

  const int NBLK = 95 * 12;   // 95 rows x 12 col-blocks (8 groups each, 2/wave)
  bm3d_pass<0><<<NBLK, 256, 0, stream>>>(img, nullptr, pvar, num1, den1);
  div_kernel<<<(NPIX + 255) / 256, 256, 0, stream>>>(num1, den1, basic, NPIX);
  bm3d_pass<1><<<NBLK, 256, 0, stream>>>(img, basic, pvar, num2, den2);
  div_kernel<<<(NPIX + 255) / 256, 256, 0, stream>>>(num2, den2, out, NPIX);
}

// Round 7
// 362.389 us; speedup vs baseline: 1.2791x; 1.2791x over previous
//
#include <hip/hip_runtime.h>
#include <math.h>

#define TS 60            // LDS tile stride: 32 rows x 60 cols
#define FINF 3.4e38f

__device__ __forceinline__ int iclip(int v, int hi) {
  return v < 0 ? 0 : (v > hi ? hi : v);
}

// Exact f32 values of the reference D8 (computed in f64, cast to f32).
constexpr float CA = 0.35355339059327373f;
constexpr float K1 = 0.49039264020161522f;
constexpr float K2 = 0.46193976625564337f;
constexpr float K3 = 0.41573480615127262f;
constexpr float K4 = 0.35355339059327379f;
constexpr float K5 = 0.27778511650980111f;
constexpr float K6 = 0.19134171618254489f;
constexpr float K7 = 0.097545161008064135f;

constexpr float DCT8[8][8] = {
  { CA, CA, CA, CA, CA, CA, CA, CA},
  { K1, K3, K5, K7,-K7,-K5,-K3,-K1},
  { K2, K6,-K6,-K2,-K2,-K6, K6, K2},
  { K3,-K7,-K1,-K5, K5, K1, K7,-K3},
  { K4,-K4,-K4, K4, K4,-K4,-K4, K4},
  { K5,-K1, K7, K3,-K3,-K7, K1,-K5},
  { K6,-K2, K2,-K6,-K6, K2,-K2, K6},
  { K7,-K5, K3,-K1, K1,-K3, K5,-K7},
};

// lane-xor exchange: DPP for 1/2, ds_swizzle for 4/8/16, shfl for 32
__device__ __forceinline__ int sxor_i(int v, int m) {
  switch (m) {
    case 1:  return __builtin_amdgcn_update_dpp(0, v, 0xB1, 0xF, 0xF, true);
    case 2:  return __builtin_amdgcn_update_dpp(0, v, 0x4E, 0xF, 0xF, true);
    case 4:  return __builtin_amdgcn_ds_swizzle(v, (4 << 10) | 0x1F);
    case 8:  return __builtin_amdgcn_ds_swizzle(v, (8 << 10) | 0x1F);
    case 16: return __builtin_amdgcn_ds_swizzle(v, (16 << 10) | 0x1F);
    default: return __shfl_xor(v, 32, 64);
  }
}
__device__ __forceinline__ float sxor_f(float v, int m) {
  return __int_as_float(sxor_i(__float_as_int(v), m));
}

// broadcast from quad lane s (VALU DPP)
__device__ __forceinline__ float qbcast(float v, int s) {
  int x = __float_as_int(v), r;
  switch (s) {
    case 0:  r = __builtin_amdgcn_update_dpp(0, x, 0x00, 0xF, 0xF, true); break;
    case 1:  r = __builtin_amdgcn_update_dpp(0, x, 0x55, 0xF, 0xF, true); break;
    case 2:  r = __builtin_amdgcn_update_dpp(0, x, 0xAA, 0xF, 0xF, true); break;
    default: r = __builtin_amdgcn_update_dpp(0, x, 0xFF, 0xF, 0xF, true); break;
  }
  return __int_as_float(r);
}

// forward: row DCT (lane-local literals) then column DCT (quad mix)
__device__ __forceinline__ void fwd_rowcol(float X[2][8], float U[2][8],
                                           const float Ca0[8], const float Ca1[8]) {
#pragma unroll
  for (int r = 0; r < 2; r++)
#pragma unroll
    for (int d = 0; d < 8; d++) {
      float s = X[r][0] * DCT8[d][0];
#pragma unroll
      for (int c = 1; c < 8; c++) s += X[r][c] * DCT8[d][c];
      U[r][d] = s;
    }
#pragma unroll
  for (int r = 0; r < 2; r++)
#pragma unroll
    for (int d = 0; d < 8; d++) X[r][d] = 0.f;
#pragma unroll
  for (int b = 0; b < 8; b++)
#pragma unroll
    for (int d = 0; d < 8; d++) {
      float yb = qbcast(U[b & 1][d], b >> 1);
      X[0][d] += Ca0[b] * yb;
      X[1][d] += Ca1[b] * yb;
    }
}

// inverse: column (quad mix, D^T coeffs) then row (lane-local literals)
__device__ __forceinline__ void inv_colrow(float X[2][8], float U[2][8],
                                           const float Ct0[8], const float Ct1[8]) {
#pragma unroll
  for (int r = 0; r < 2; r++)
#pragma unroll
    for (int d = 0; d < 8; d++) U[r][d] = 0.f;
#pragma unroll
  for (int a = 0; a < 8; a++)
#pragma unroll
    for (int d = 0; d < 8; d++) {
      float za = qbcast(X[a & 1][d], a >> 1);
      U[0][d] += Ct0[a] * za;
      U[1][d] += Ct1[a] * za;
    }
#pragma unroll
  for (int r = 0; r < 2; r++)
#pragma unroll
    for (int c = 0; c < 8; c++) {
      float s = U[r][0] * DCT8[0][c];
#pragma unroll
      for (int d = 1; d < 8; d++) s += U[r][d] * DCT8[d][c];
      X[r][c] = s;
    }
}

// fused 2-group 16-point Walsh-Hadamard across lane bits 2..5, scale 1/4
__device__ __forceinline__ void had16r2(float X0[2][8], float X1[2][8], int lane) {
#pragma unroll
  for (int m = 4; m <= 32; m <<= 1) {
    bool hi = (lane & m) != 0;
#pragma unroll
    for (int r = 0; r < 2; r++)
#pragma unroll
      for (int d = 0; d < 8; d++) {
        float t0 = sxor_f(X0[r][d], m);
        float t1 = sxor_f(X1[r][d], m);
        X0[r][d] = hi ? (t0 - X0[r][d]) : (X0[r][d] + t0);
        X1[r][d] = hi ? (t1 - X1[r][d]) : (X1[r][d] + t1);
      }
  }
#pragma unroll
  for (int r = 0; r < 2; r++)
#pragma unroll
    for (int d = 0; d < 8; d++) { X0[r][d] *= 0.25f; X1[r][d] *= 0.25f; }
}

template <int WIEN>
__global__ __launch_bounds__(256, 2) void bm3d_pass(
    const int* __restrict__ img, const float* __restrict__ basic,
    const int* __restrict__ pvar,
    float* __restrict__ num, float* __restrict__ den) {
  __shared__ float ldsD[64], ldsDT[64];
  __shared__ __align__(16) float wdist[8][84];
  __shared__ int wsel[8][16];
  __shared__ float bufA[32 * TS];  // step1: tileN -> accN | step2: tileB -> accN
  __shared__ float bufB[32 * TS];  // step1: ......-> accD | step2: tileN -> accD

  int t = threadIdx.x;
  int brow = blockIdx.x / 12, bcb = blockIdx.x - brow * 12;
  int ri = brow * 4;
  int bim = ri - 12;       int bi = bim < 0 ? 0 : (bim > 352 ? 352 : bim);
  int ubm = 32 * bcb - 12; int ub = ubm < 0 ? 0 : (ubm > 324 ? 324 : ubm);

  if (t < 64) ldsD[t] = DCT8[t >> 3][t & 7];
  else if (t < 128) { int u = t - 64; ldsDT[u] = DCT8[u & 7][u >> 3]; }

  // tile load: 480 float4/int4 rows-of-15, always in range
  for (int e4 = t; e4 < 480; e4 += 256) {
    int r = e4 / 15, c4 = (e4 - r * 15) << 2;
    int gidx = (bi + r) * 384 + ub + c4;
    int o = r * TS + c4;
    int4 iv = *(const int4*)&img[gidx];
    float4 fv = make_float4((float)iv.x, (float)iv.y, (float)iv.z, (float)iv.w);
    if (WIEN) {
      *(float4*)&bufA[o] = *(const float4*)&basic[gidx];
      *(float4*)&bufB[o] = fv;
    } else {
      *(float4*)&bufA[o] = fv;
    }
  }
  __syncthreads();

  float sigma2 = (float)pvar[0];
  int wv = t >> 6, lane = t & 63;
  int s0 = 2 * wv, s1 = 2 * wv + 1;
  int g0 = bcb * 8 + 2 * wv, g1 = g0 + 1;
  bool active0 = g0 < 95, active1 = g1 < 95;
  int rj0 = (active0 ? g0 : 94) * 4;
  int rj1 = (active1 ? g1 : 94) * 4;

  const float* tileS = bufA;                 // match source (basic in step2)
  const float* tileN = WIEN ? bufB : bufA;   // noisy pixels

  // ---------- block match: 2 groups x (candidate lane, candidate 64+lane) ----
  int cB = lane < 17 ? 64 + lane : 80;
  int oiA = (lane / 9) * 3 - 12, ojA = (lane % 9) * 3 - 12;
  int oiB = (cB / 9) * 3 - 12,   ojB = (cB % 9) * 3 - 12;
  int aiA = iclip(ri + oiA, 376) - bi;
  int aiB = iclip(ri + oiB, 376) - bi;
  int ajA0 = iclip(rj0 + ojA, 376) - ub, ajA1 = iclip(rj1 + ojA, 376) - ub;
  int ajB0 = iclip(rj0 + ojB, 376) - ub, ajB1 = iclip(rj1 + ojB, 376) - ub;
  int roi = ri - bi, roj0 = rj0 - ub, roj1 = rj1 - ub;

  float sA0c = 0.f, sA0r = 0.f, sB0c = 0.f, sB0r = 0.f;
  float sA1c = 0.f, sA1r = 0.f, sB1c = 0.f, sB1r = 0.f;
  float srr0 = 0.f, srr1 = 0.f;
#pragma unroll
  for (int i = 0; i < 8; i++) {
    // ref rows: 16B-aligned (roj multiple of 4, TS multiple of 4)
    float4 r0a = *(const float4*)(tileS + (roi + i) * TS + roj0);
    float4 r0b = *(const float4*)(tileS + (roi + i) * TS + roj0 + 4);
    float4 r1a = *(const float4*)(tileS + (roi + i) * TS + roj1);
    float4 r1b = *(const float4*)(tileS + (roi + i) * TS + roj1 + 4);
    float rv0[8] = {r0a.x, r0a.y, r0a.z, r0a.w, r0b.x, r0b.y, r0b.z, r0b.w};
    float rv1[8] = {r1a.x, r1a.y, r1a.z, r1a.w, r1b.x, r1b.y, r1b.z, r1b.w};
    const float* a0p = tileS + (aiA + i) * TS + ajA0;
    const float* a1p = tileS + (aiA + i) * TS + ajA1;
    const float* b0p = tileS + (aiB + i) * TS + ajB0;
    const float* b1p = tileS + (aiB + i) * TS + ajB1;
#pragma unroll
    for (int j = 0; j < 8; j++) {
      float a0 = a0p[j], a1 = a1p[j], b0 = b0p[j], b1 = b1p[j];
      sA0c += a0 * a0; sA0r += a0 * rv0[j];
      sA1c += a1 * a1; sA1r += a1 * rv1[j];
      sB0c += b0 * b0; sB0r += b0 * rv0[j];
      sB1c += b1 * b1; sB1r += b1 * rv1[j];
      srr0 += rv0[j] * rv0[j]; srr1 += rv1[j] * rv1[j];
    }
  }
  float dA0 = sA0c - 2.f * sA0r + srr0;
  float dA1 = sA1c - 2.f * sA1r + srr1;
  float dB0 = lane < 17 ? (sB0c - 2.f * sB0r + srr0) : FINF;
  float dB1 = lane < 17 ? (sB1c - 2.f * sB1r + srr1) : FINF;

  // wave-local distance tables (no block barrier needed: same-wave LDS RAW)
  wdist[s0][lane] = dA0;
  wdist[s1][lane] = dA1;
  if (lane < 17)      { wdist[s0][64 + lane] = dB0; wdist[s1][64 + lane] = dB1; }
  else if (lane < 20) { wdist[s0][64 + lane] = FINF; wdist[s1][64 + lane] = FINF; }

  // ---------- rank-count top-16 (lexicographic (d, idx) = lax.top_k order) ----
  int rA0 = 0, rB0 = 0, rA1 = 0, rB1 = 0;
  const float4* wp0 = (const float4*)&wdist[s0][0];
  const float4* wp1 = (const float4*)&wdist[s1][0];
  int idxA = lane, idxB = 64 + lane;
#pragma unroll 3
  for (int c4 = 0; c4 < 21; c4++) {
    float4 v0 = wp0[c4], v1 = wp1[c4];
    float e0[4] = {v0.x, v0.y, v0.z, v0.w};
    float e1[4] = {v1.x, v1.y, v1.z, v1.w};
#pragma unroll
    for (int u = 0; u < 4; u++) {
      int c2 = c4 * 4 + u;
      rA0 += (e0[u] < dA0 || (e0[u] == dA0 && c2 < idxA)) ? 1 : 0;
      rB0 += (e0[u] < dB0 || (e0[u] == dB0 && c2 < idxB)) ? 1 : 0;
      rA1 += (e1[u] < dA1 || (e1[u] == dA1 && c2 < idxA)) ? 1 : 0;
      rB1 += (e1[u] < dB1 || (e1[u] == dB1 && c2 < idxB)) ? 1 : 0;
    }
  }
  if (rA0 < 16) wsel[s0][rA0] = (aiA << 8) | ajA0;
  if (rA1 < 16) wsel[s1][rA1] = (aiA << 8) | ajA1;
  if (lane < 17) {
    if (rB0 < 16) wsel[s0][rB0] = (aiB << 8) | ajB0;
    if (rB1 < 16) wsel[s1][rB1] = (aiB << 8) | ajB1;
  }

  // ---------- per-lane geometry + coefficients (float4 loads) ----------
  int k = lane >> 2, q = lane & 3;
  int sp0 = wsel[s0][k], sp1 = wsel[s1][k];
  int gi0 = (sp0 >> 8) + 2 * q, gj0 = sp0 & 255;
  int gi1 = (sp1 >> 8) + 2 * q, gj1 = sp1 & 255;

  float Ca0[8], Ca1[8];
  *(float4*)&Ca0[0] = *(const float4*)&ldsD[(2 * q) * 8];
  *(float4*)&Ca0[4] = *(const float4*)&ldsD[(2 * q) * 8 + 4];
  *(float4*)&Ca1[0] = *(const float4*)&ldsD[(2 * q + 1) * 8];
  *(float4*)&Ca1[4] = *(const float4*)&ldsD[(2 * q + 1) * 8 + 4];

  float X0[2][8], X1[2][8], U[2][8];
  float w0, w1;

  if (WIEN) {
    float Z0[2][8], Z1[2][8];
#pragma unroll
    for (int r = 0; r < 2; r++)
#pragma unroll
      for (int c = 0; c < 8; c++) {
        Z0[r][c] = tileS[(gi0 + r) * TS + gj0 + c];
        Z1[r][c] = tileS[(gi1 + r) * TS + gj1 + c];
      }
    fwd_rowcol(Z0, U, Ca0, Ca1);
    fwd_rowcol(Z1, U, Ca0, Ca1);
    had16r2(Z0, Z1, lane);                       // cb for both groups

#pragma unroll
    for (int r = 0; r < 2; r++)
#pragma unroll
      for (int c = 0; c < 8; c++) {
        X0[r][c] = tileN[(gi0 + r) * TS + gj0 + c];
        X1[r][c] = tileN[(gi1 + r) * TS + gj1 + c];
      }
    fwd_rowcol(X0, U, Ca0, Ca1);
    fwd_rowcol(X1, U, Ca0, Ca1);
    had16r2(X0, X1, lane);                       // cn for both groups

    float p0 = 0.f, p1 = 0.f;
#pragma unroll
    for (int r = 0; r < 2; r++)
#pragma unroll
      for (int d = 0; d < 8; d++) {
        float cb0 = Z0[r][d], cb1 = Z1[r][d];
        float we0 = cb0 * cb0 / (cb0 * cb0 + sigma2);
        float we1 = cb1 * cb1 / (cb1 * cb1 + sigma2);
        X0[r][d] = we0 * X0[r][d];
        X1[r][d] = we1 * X1[r][d];
        p0 += we0 * we0; p1 += we1 * we1;
      }
#pragma unroll
    for (int m = 1; m <= 32; m <<= 1) { p0 += sxor_f(p0, m); p1 += sxor_f(p1, m); }
    w0 = 1.f / (sigma2 * fmaxf(p0, 1e-8f));
    w1 = 1.f / (sigma2 * fmaxf(p1, 1e-8f));
  } else {
#pragma unroll
    for (int r = 0; r < 2; r++)
#pragma unroll
      for (int c = 0; c < 8; c++) {
        X0[r][c] = tileN[(gi0 + r) * TS + gj0 + c];
        X1[r][c] = tileN[(gi1 + r) * TS + gj1 + c];
      }
    fwd_rowcol(X0, U, Ca0, Ca1);
    fwd_rowcol(X1, U, Ca0, Ca1);
    had16r2(X0, X1, lane);

    float thr = 2.7f * sqrtf(sigma2);
    int cnt0 = 0, cnt1 = 0;
#pragma unroll
    for (int r = 0; r < 2; r++)
#pragma unroll
      for (int d = 0; d < 8; d++) {
        bool dc = (lane == 0 && r == 0 && d == 0);
        bool k0 = (fabsf(X0[r][d]) > thr) || dc;
        bool k1 = (fabsf(X1[r][d]) > thr) || dc;
        cnt0 += (int)__popcll(__ballot(k0));
        cnt1 += (int)__popcll(__ballot(k1));
        if (!k0) X0[r][d] = 0.f;
        if (!k1) X1[r][d] = 0.f;
      }
    w0 = 1.f / (sigma2 * fmaxf((float)cnt0, 1.f));
    w1 = 1.f / (sigma2 * fmaxf((float)cnt1, 1.f));
  }

  had16r2(X0, X1, lane);
#pragma unroll
  for (int a = 0; a < 8; a++) {        // D^T rows for this lane's two b's
    Ca0[a] = ldsDT[(2 * q) * 8 + a];
    Ca1[a] = ldsDT[(2 * q + 1) * 8 + a];
  }
  inv_colrow(X0, U, Ca0, Ca1);
  inv_colrow(X1, U, Ca0, Ca1);

  // ---------- overlay: tiles dead, reuse as num/den accumulators ----------
  __syncthreads();
  for (int e = t; e < 32 * TS; e += 256) { bufA[e] = 0.f; bufB[e] = 0.f; }
  __syncthreads();

  if (active0) {
#pragma unroll
    for (int r = 0; r < 2; r++)
#pragma unroll
      for (int c = 0; c < 8; c++) {
        int off = (gi0 + r) * TS + gj0 + c;
        atomicAdd(&bufA[off], w0 * X0[r][c]);
        atomicAdd(&bufB[off], w0);
      }
  }
  if (active1) {
#pragma unroll
    for (int r = 0; r < 2; r++)
#pragma unroll
      for (int c = 0; c < 8; c++) {
        int off = (gi1 + r) * TS + gj1 + c;
        atomicAdd(&bufA[off], w1 * X1[r][c]);
        atomicAdd(&bufB[off], w1);
      }
  }
  __syncthreads();

  for (int e = t; e < 32 * TS; e += 256) {
    float dv = bufB[e];
    if (dv != 0.f) {
      int r = e / TS, c = e - r * TS;
      int gp = (bi + r) * 384 + ub + c;
      atomicAdd(&num[gp], bufA[e]);
      atomicAdd(&den[gp], dv);
    }
  }
}

__global__ void div_kernel(const float* __restrict__ num,
                           const float* __restrict__ den,
                           float* __restrict__ out, int npix) {
  int i = blockIdx.x * blockDim.x + threadIdx.x;
  if (i < npix) out[i] = num[i] / fmaxf(den[i], 1e-8f);
}

extern "C" void kernel_launch(void* const* d_in, const int* in_sizes, int n_in,
                              void* d_out, int out_size, void* d_ws, size_t ws_size,
                              hipStream_t stream) {
  const int* img  = (const int*)d_in[0];
  const int* pvar = (const int*)d_in[1];
  float* out = (float*)d_out;
  float* ws  = (float*)d_ws;

  const int NPIX = 384 * 384;
  float* num1  = ws + 0 * NPIX;
  float* den1  = ws + 1 * NPIX;
  float* basic = ws + 2 * NPIX;
  float* num2  = ws + 3 * NPIX;
  float* den2  = ws + 4 * NPIX;

  hipMemsetAsync(num1, 0, (size_t)2 * NPIX * sizeof(float), stream);
  hipMemsetAsync(num2, 0, (size_t)2 * NPIX * sizeof(float), stream);

  const int NBLK = 95 * 12;   // 95 rows x 12 col-blocks (8 groups each, 2/wave)
  bm3d_pass<0><<<NBLK, 256, 0, stream>>>(img, nullptr, pvar, num1, den1);
  div_kernel<<<(NPIX + 255) / 256, 256, 0, stream>>>(num1, den1, basic, NPIX);
  bm3d_pass<1><<<NBLK, 256, 0, stream>>>(img, basic, pvar, num2, den2);
  div_kernel<<<(NPIX + 255) / 256, 256, 0, stream>>>(num2, den2, out, NPIX);
}

// Round 8
// 314.163 us; speedup vs baseline: 1.4755x; 1.1535x over previous
//
#include <hip/hip_runtime.h>
#include <math.h>

#define TS 48            // LDS tile stride: 32 rows x 44 used cols
#define FINF 3.4e38f

__device__ __forceinline__ int iclip(int v, int hi) {
  return v < 0 ? 0 : (v > hi ? hi : v);
}

// Exact f32 values of the reference D8 (computed in f64, cast to f32).
constexpr float CA = 0.35355339059327373f;
constexpr float K1 = 0.49039264020161522f;
constexpr float K2 = 0.46193976625564337f;
constexpr float K3 = 0.41573480615127262f;
constexpr float K4 = 0.35355339059327379f;
constexpr float K5 = 0.27778511650980111f;
constexpr float K6 = 0.19134171618254489f;
constexpr float K7 = 0.097545161008064135f;

constexpr float DCT8[8][8] = {
  { CA, CA, CA, CA, CA, CA, CA, CA},
  { K1, K3, K5, K7,-K7,-K5,-K3,-K1},
  { K2, K6,-K6,-K2,-K2,-K6, K6, K2},
  { K3,-K7,-K1,-K5, K5, K1, K7,-K3},
  { K4,-K4,-K4, K4, K4,-K4,-K4, K4},
  { K5,-K1, K7, K3,-K3,-K7, K1,-K5},
  { K6,-K2, K2,-K6,-K6, K2,-K2, K6},
  { K7,-K5, K3,-K1, K1,-K3, K5,-K7},
};

// lane-xor exchange: DPP for 1/2/8, ds_swizzle for 4/16, bpermute for 32
__device__ __forceinline__ int sxor_i(int v, int m) {
  switch (m) {
    case 1:  return __builtin_amdgcn_update_dpp(0, v, 0xB1, 0xF, 0xF, true);  // quad_perm [1,0,3,2]
    case 2:  return __builtin_amdgcn_update_dpp(0, v, 0x4E, 0xF, 0xF, true);  // quad_perm [2,3,0,1]
    case 4:  return __builtin_amdgcn_ds_swizzle(v, (4 << 10) | 0x1F);
    case 8:  return __builtin_amdgcn_update_dpp(0, v, 0x128, 0xF, 0xF, true); // row_ror:8 == xor 8 in 16
    case 16: return __builtin_amdgcn_ds_swizzle(v, (16 << 10) | 0x1F);
    default: return __shfl_xor(v, 32, 64);
  }
}
__device__ __forceinline__ float sxor_f(float v, int m) {
  return __int_as_float(sxor_i(__float_as_int(v), m));
}

// broadcast from quad lane s (VALU DPP)
__device__ __forceinline__ float qbcast(float v, int s) {
  int x = __float_as_int(v), r;
  switch (s) {
    case 0:  r = __builtin_amdgcn_update_dpp(0, x, 0x00, 0xF, 0xF, true); break;
    case 1:  r = __builtin_amdgcn_update_dpp(0, x, 0x55, 0xF, 0xF, true); break;
    case 2:  r = __builtin_amdgcn_update_dpp(0, x, 0xAA, 0xF, 0xF, true); break;
    default: r = __builtin_amdgcn_update_dpp(0, x, 0xFF, 0xF, 0xF, true); break;
  }
  return __int_as_float(r);
}

// forward: row DCT (lane-local literals) then column DCT (quad mix)
__device__ __forceinline__ void fwd_rowcol(float X[2][8], float U[2][8],
                                           const float Ca0[8], const float Ca1[8]) {
#pragma unroll
  for (int r = 0; r < 2; r++)
#pragma unroll
    for (int d = 0; d < 8; d++) {
      float s = X[r][0] * DCT8[d][0];
#pragma unroll
      for (int c = 1; c < 8; c++) s += X[r][c] * DCT8[d][c];
      U[r][d] = s;
    }
#pragma unroll
  for (int r = 0; r < 2; r++)
#pragma unroll
    for (int d = 0; d < 8; d++) X[r][d] = 0.f;
#pragma unroll
  for (int b = 0; b < 8; b++)
#pragma unroll
    for (int d = 0; d < 8; d++) {
      float yb = qbcast(U[b & 1][d], b >> 1);
      X[0][d] += Ca0[b] * yb;
      X[1][d] += Ca1[b] * yb;
    }
}

// inverse: column (quad mix, D^T coeffs) then row (lane-local literals)
__device__ __forceinline__ void inv_colrow(float X[2][8], float U[2][8],
                                           const float Ct0[8], const float Ct1[8]) {
#pragma unroll
  for (int r = 0; r < 2; r++)
#pragma unroll
    for (int d = 0; d < 8; d++) U[r][d] = 0.f;
#pragma unroll
  for (int a = 0; a < 8; a++)
#pragma unroll
    for (int d = 0; d < 8; d++) {
      float za = qbcast(X[a & 1][d], a >> 1);
      U[0][d] += Ct0[a] * za;
      U[1][d] += Ct1[a] * za;
    }
#pragma unroll
  for (int r = 0; r < 2; r++)
#pragma unroll
    for (int c = 0; c < 8; c++) {
      float s = U[r][0] * DCT8[0][c];
#pragma unroll
      for (int d = 1; d < 8; d++) s += U[r][d] * DCT8[d][c];
      X[r][c] = s;
    }
}

// 16-point Walsh-Hadamard across lane bits 2..5, scale 1/4
__device__ __forceinline__ void had16r(float X[2][8], int lane) {
#pragma unroll
  for (int m = 4; m <= 32; m <<= 1) {
    bool hi = (lane & m) != 0;
#pragma unroll
    for (int r = 0; r < 2; r++)
#pragma unroll
      for (int d = 0; d < 8; d++) {
        float tv = sxor_f(X[r][d], m);
        X[r][d] = hi ? (tv - X[r][d]) : (X[r][d] + tv);
      }
  }
#pragma unroll
  for (int r = 0; r < 2; r++)
#pragma unroll
    for (int d = 0; d < 8; d++) X[r][d] *= 0.25f;
}

template <int WIEN>
__global__ __launch_bounds__(256, 4) void bm3d_pass(
    const int* __restrict__ img, const float* __restrict__ basic,
    const int* __restrict__ pvar,
    float* __restrict__ num, float* __restrict__ den) {
  __shared__ float ldsD[64], ldsDT[64];
  __shared__ __align__(16) float wdist[4][84];
  __shared__ int wsel[4][16];
  __shared__ float Rws[32 * 40];     // row box sums of squared tile
  __shared__ float S2[25 * 40];      // 8x8 box sums of squared tile
  __shared__ float bufA[32 * TS];    // tileS -> accN overlay
  __shared__ float bufB[32 * TS];    // tileN (step2) -> accD overlay

  int t = threadIdx.x;
  int brow = blockIdx.x / 24, bcb = blockIdx.x - brow * 24;
  int ri = brow * 4;
  int bim = ri - 12;       int bi = bim < 0 ? 0 : (bim > 352 ? 352 : bim);
  int ubm = 16 * bcb - 12; int ub = ubm < 0 ? 0 : (ubm > 352 ? 352 : ubm);

  if (t < 64) ldsD[t] = DCT8[t >> 3][t & 7];
  else if (t < 128) { int u = t - 64; ldsDT[u] = DCT8[u & 7][u >> 3]; }

  // ---- tile load: 32 rows x 11 float4 (44 cols), guard right edge ----
  for (int e4 = t; e4 < 352; e4 += 256) {
    int r = e4 / 11, c4 = (e4 - r * 11) << 2;
    int col = ub + c4;
    int gidx = (bi + r) * 384 + col;
    int o = r * TS + c4;
    if (col + 3 < 384) {
      int4 iv = *(const int4*)&img[gidx];
      float4 fv = make_float4((float)iv.x, (float)iv.y, (float)iv.z, (float)iv.w);
      if (WIEN) {
        *(float4*)&bufA[o] = *(const float4*)&basic[gidx];
        *(float4*)&bufB[o] = fv;
      } else {
        *(float4*)&bufA[o] = fv;
      }
    } else {
#pragma unroll
      for (int u = 0; u < 4; u++) {
        bool ok = (col + u) < 384;
        float fi = ok ? (float)img[gidx + u] : 0.f;
        if (WIEN) {
          bufA[o + u] = ok ? basic[gidx + u] : 0.f;
          bufB[o + u] = fi;
        } else {
          bufA[o + u] = fi;
        }
      }
    }
  }
  __syncthreads();

  // ---- box sums of squared match-source tile (separable) ----
  for (int e = t; e < 32 * 37; e += 256) {
    int r = e / 37, j = e - r * 37;
    const float* p = bufA + r * TS + j;
    float s = 0.f;
#pragma unroll
    for (int d = 0; d < 8; d++) { float v = p[d]; s += v * v; }
    Rws[r * 40 + j] = s;
  }
  __syncthreads();
  for (int e = t; e < 25 * 37; e += 256) {
    int i = e / 37, j = e - i * 37;
    float s = 0.f;
#pragma unroll
    for (int d = 0; d < 8; d++) s += Rws[(i + d) * 40 + j];
    S2[i * 40 + j] = s;
  }
  __syncthreads();

  float sigma2 = (float)pvar[0];
  int wv = t >> 6, lane = t & 63;
  int gc = bcb * 4 + wv;
  bool active = gc < 95;
  int rj = (active ? gc : 94) * 4;

  const float* tileS = bufA;                 // match source (basic in step2)
  const float* tileN = WIEN ? bufB : bufA;   // noisy pixels

  // ---- match: scr only (scc/srr from S2), candidates lane & 64+lane ----
  int cB = lane < 17 ? 64 + lane : 80;
  int aiA = iclip(ri + (lane / 9) * 3 - 12, 376) - bi;
  int ajA = iclip(rj + (lane % 9) * 3 - 12, 376) - ub;
  int aiB = iclip(ri + (cB / 9) * 3 - 12, 376) - bi;
  int ajB = iclip(rj + (cB % 9) * 3 - 12, 376) - ub;
  int roi = ri - bi, roj = rj - ub;

  float scrA = 0.f, scrB = 0.f;
#pragma unroll
  for (int i = 0; i < 8; i++) {
    float4 ra = *(const float4*)(tileS + (roi + i) * TS + roj);      // roj % 4 == 0
    float4 rb = *(const float4*)(tileS + (roi + i) * TS + roj + 4);
    float rv[8] = {ra.x, ra.y, ra.z, ra.w, rb.x, rb.y, rb.z, rb.w};
    const float* ap = tileS + (aiA + i) * TS + ajA;
    const float* bp = tileS + (aiB + i) * TS + ajB;
#pragma unroll
    for (int j = 0; j < 8; j++) {
      scrA += ap[j] * rv[j];
      scrB += bp[j] * rv[j];
    }
  }
  float srr = S2[roi * 40 + roj];
  float dA = fmaf(-2.f, scrA, S2[aiA * 40 + ajA]) + srr;
  float dB = lane < 17 ? fmaf(-2.f, scrB, S2[aiB * 40 + ajB]) + srr : FINF;

  // wave-local distance table (same-wave LDS RAW, no block barrier)
  wdist[wv][lane] = dA;
  if (lane < 17)      wdist[wv][64 + lane] = dB;
  else if (lane < 20) wdist[wv][64 + lane] = FINF;

  // ---- rank-count top-16 (lexicographic (d, idx) = lax.top_k order) ----
  int rA = 0, rB = 0;
  const float4* wp = (const float4*)&wdist[wv][0];
  int idxB = 64 + lane;
#pragma unroll 3
  for (int c4 = 0; c4 < 21; c4++) {
    float4 v = wp[c4];
    float ev[4] = {v.x, v.y, v.z, v.w};
#pragma unroll
    for (int u = 0; u < 4; u++) {
      int c2 = c4 * 4 + u;
      rA += (ev[u] < dA || (ev[u] == dA && c2 < lane)) ? 1 : 0;
      rB += (ev[u] < dB || (ev[u] == dB && c2 < idxB)) ? 1 : 0;
    }
  }
  if (rA < 16) wsel[wv][rA] = (aiA << 8) | ajA;
  if (lane < 17 && rB < 16) wsel[wv][rB] = (aiB << 8) | ajB;

  // ---- per-lane geometry + coefficients ----
  int k = lane >> 2, q = lane & 3;
  int sp = wsel[wv][k];
  int gi0 = (sp >> 8) + 2 * q, gj0 = sp & 255;

  float Ca0[8], Ca1[8];
  *(float4*)&Ca0[0] = *(const float4*)&ldsD[(2 * q) * 8];
  *(float4*)&Ca0[4] = *(const float4*)&ldsD[(2 * q) * 8 + 4];
  *(float4*)&Ca1[0] = *(const float4*)&ldsD[(2 * q + 1) * 8];
  *(float4*)&Ca1[4] = *(const float4*)&ldsD[(2 * q + 1) * 8 + 4];

  float X[2][8], U[2][8];
  float w;

  if (WIEN) {
    float Z[2][8];
#pragma unroll
    for (int r = 0; r < 2; r++)
#pragma unroll
      for (int c = 0; c < 8; c++) Z[r][c] = tileS[(gi0 + r) * TS + gj0 + c];
    fwd_rowcol(Z, U, Ca0, Ca1);
    had16r(Z, lane);                          // cb

#pragma unroll
    for (int r = 0; r < 2; r++)
#pragma unroll
      for (int c = 0; c < 8; c++) X[r][c] = tileN[(gi0 + r) * TS + gj0 + c];
    fwd_rowcol(X, U, Ca0, Ca1);
    had16r(X, lane);                          // cn

    float p = 0.f;
#pragma unroll
    for (int r = 0; r < 2; r++)
#pragma unroll
      for (int d = 0; d < 8; d++) {
        float cb = Z[r][d];
        float we = cb * cb / (cb * cb + sigma2);
        X[r][d] = we * X[r][d];
        p += we * we;
      }
#pragma unroll
    for (int m = 1; m <= 32; m <<= 1) p += sxor_f(p, m);
    w = 1.f / (sigma2 * fmaxf(p, 1e-8f));
  } else {
#pragma unroll
    for (int r = 0; r < 2; r++)
#pragma unroll
      for (int c = 0; c < 8; c++) X[r][c] = tileN[(gi0 + r) * TS + gj0 + c];
    fwd_rowcol(X, U, Ca0, Ca1);
    had16r(X, lane);

    float thr = 2.7f * sqrtf(sigma2);
    int cnt = 0;
#pragma unroll
    for (int r = 0; r < 2; r++)
#pragma unroll
      for (int d = 0; d < 8; d++) {
        bool keep = (fabsf(X[r][d]) > thr) || (lane == 0 && r == 0 && d == 0);
        cnt += (int)__popcll(__ballot(keep));
        if (!keep) X[r][d] = 0.f;
      }
    w = 1.f / (sigma2 * fmaxf((float)cnt, 1.f));
  }

  had16r(X, lane);
#pragma unroll
  for (int a = 0; a < 8; a++) {        // D^T rows for this lane's two b's
    Ca0[a] = ldsDT[(2 * q) * 8 + a];
    Ca1[a] = ldsDT[(2 * q + 1) * 8 + a];
  }
  inv_colrow(X, U, Ca0, Ca1);

  // ---- overlay: tiles dead, reuse as num/den accumulators ----
  __syncthreads();
  for (int e = t; e < 32 * TS; e += 256) { bufA[e] = 0.f; bufB[e] = 0.f; }
  __syncthreads();

  if (active) {
#pragma unroll
    for (int r = 0; r < 2; r++)
#pragma unroll
      for (int c = 0; c < 8; c++) {
        int off = (gi0 + r) * TS + gj0 + c;
        atomicAdd(&bufA[off], w * X[r][c]);
        atomicAdd(&bufB[off], w);
      }
  }
  __syncthreads();

  for (int e = t; e < 32 * TS; e += 256) {
    float dv = bufB[e];
    if (dv != 0.f) {
      int r = e / TS, c = e - r * TS;
      int gp = (bi + r) * 384 + ub + c;
      atomicAdd(&num[gp], bufA[e]);
      atomicAdd(&den[gp], dv);
    }
  }
}

__global__ void div_kernel(const float* __restrict__ num,
                           const float* __restrict__ den,
                           float* __restrict__ out, int npix) {
  int i = blockIdx.x * blockDim.x + threadIdx.x;
  if (i < npix) out[i] = num[i] / fmaxf(den[i], 1e-8f);
}

extern "C" void kernel_launch(void* const* d_in, const int* in_sizes, int n_in,
                              void* d_out, int out_size, void* d_ws, size_t ws_size,
                              hipStream_t stream) {
  const int* img  = (const int*)d_in[0];
  const int* pvar = (const int*)d_in[1];
  float* out = (float*)d_out;
  float* ws  = (float*)d_ws;

  const int NPIX = 384 * 384;
  float* num1  = ws + 0 * NPIX;
  float* den1  = ws + 1 * NPIX;
  float* basic = ws + 2 * NPIX;
  float* num2  = ws + 3 * NPIX;
  float* den2  = ws + 4 * NPIX;

  hipMemsetAsync(num1, 0, (size_t)2 * NPIX * sizeof(float), stream);
  hipMemsetAsync(num2, 0, (size_t)2 * NPIX * sizeof(float), stream);

  const int NBLK = 95 * 24;   // 95 rows x 24 col-blocks (4 groups each)
  bm3d_pass<0><<<NBLK, 256, 0, stream>>>(img, nullptr, pvar, num1, den1);
  div_kernel<<<(NPIX + 255) / 256, 256, 0, stream>>>(num1, den1, basic, NPIX);
  bm3d_pass<1><<<NBLK, 256, 0, stream>>>(img, basic, pvar, num2, den2);
  div_kernel<<<(NPIX + 255) / 256, 256, 0, stream>>>(num2, den2, out, NPIX);
}

// Round 9
// 302.326 us; speedup vs baseline: 1.5333x; 1.0392x over previous
//
#include <hip/hip_runtime.h>
#include <math.h>

#define TS 52            // LDS tile stride: 32 rows x 44 used cols (+pad)
#define FINF 3.4e38f

__device__ __forceinline__ int iclip(int v, int hi) {
  return v < 0 ? 0 : (v > hi ? hi : v);
}

// Exact f32 values of the reference D8 (computed in f64, cast to f32).
constexpr float CA = 0.35355339059327373f;
constexpr float K1 = 0.49039264020161522f;
constexpr float K2 = 0.46193976625564337f;
constexpr float K3 = 0.41573480615127262f;
constexpr float K4 = 0.35355339059327379f;
constexpr float K5 = 0.27778511650980111f;
constexpr float K6 = 0.19134171618254489f;
constexpr float K7 = 0.097545161008064135f;

constexpr float DCT8[8][8] = {
  { CA, CA, CA, CA, CA, CA, CA, CA},
  { K1, K3, K5, K7,-K7,-K5,-K3,-K1},
  { K2, K6,-K6,-K2,-K2,-K6, K6, K2},
  { K3,-K7,-K1,-K5, K5, K1, K7,-K3},
  { K4,-K4,-K4, K4, K4,-K4,-K4, K4},
  { K5,-K1, K7, K3,-K3,-K7, K1,-K5},
  { K6,-K2, K2,-K6,-K6, K2,-K2, K6},
  { K7,-K5, K3,-K1, K1,-K3, K5,-K7},
};

// lane-xor exchange: DPP for 1/2/8, ds_swizzle for 4/16, shfl for 32
__device__ __forceinline__ int sxor_i(int v, int m) {
  switch (m) {
    case 1:  return __builtin_amdgcn_update_dpp(0, v, 0xB1, 0xF, 0xF, true);  // quad_perm [1,0,3,2]
    case 2:  return __builtin_amdgcn_update_dpp(0, v, 0x4E, 0xF, 0xF, true);  // quad_perm [2,3,0,1]
    case 4:  return __builtin_amdgcn_ds_swizzle(v, (4 << 10) | 0x1F);
    case 8:  return __builtin_amdgcn_update_dpp(0, v, 0x128, 0xF, 0xF, true); // row_ror:8 == xor 8 in 16
    case 16: return __builtin_amdgcn_ds_swizzle(v, (16 << 10) | 0x1F);
    default: return __shfl_xor(v, 32, 64);
  }
}
__device__ __forceinline__ float sxor_f(float v, int m) {
  return __int_as_float(sxor_i(__float_as_int(v), m));
}

// broadcast from quad lane s (VALU DPP)
__device__ __forceinline__ float qbcast(float v, int s) {
  int x = __float_as_int(v), r;
  switch (s) {
    case 0:  r = __builtin_amdgcn_update_dpp(0, x, 0x00, 0xF, 0xF, true); break;
    case 1:  r = __builtin_amdgcn_update_dpp(0, x, 0x55, 0xF, 0xF, true); break;
    case 2:  r = __builtin_amdgcn_update_dpp(0, x, 0xAA, 0xF, 0xF, true); break;
    default: r = __builtin_amdgcn_update_dpp(0, x, 0xFF, 0xF, 0xF, true); break;
  }
  return __int_as_float(r);
}

// forward: row DCT (lane-local literals) then column DCT (quad mix)
__device__ __forceinline__ void fwd_rowcol(float X[2][8], float U[2][8],
                                           const float Ca0[8], const float Ca1[8]) {
#pragma unroll
  for (int r = 0; r < 2; r++)
#pragma unroll
    for (int d = 0; d < 8; d++) {
      float s = X[r][0] * DCT8[d][0];
#pragma unroll
      for (int c = 1; c < 8; c++) s += X[r][c] * DCT8[d][c];
      U[r][d] = s;
    }
#pragma unroll
  for (int r = 0; r < 2; r++)
#pragma unroll
    for (int d = 0; d < 8; d++) X[r][d] = 0.f;
#pragma unroll
  for (int b = 0; b < 8; b++)
#pragma unroll
    for (int d = 0; d < 8; d++) {
      float yb = qbcast(U[b & 1][d], b >> 1);
      X[0][d] += Ca0[b] * yb;
      X[1][d] += Ca1[b] * yb;
    }
}

// inverse: column (quad mix, D^T coeffs) then row (lane-local literals)
__device__ __forceinline__ void inv_colrow(float X[2][8], float U[2][8],
                                           const float Ct0[8], const float Ct1[8]) {
#pragma unroll
  for (int r = 0; r < 2; r++)
#pragma unroll
    for (int d = 0; d < 8; d++) U[r][d] = 0.f;
#pragma unroll
  for (int a = 0; a < 8; a++)
#pragma unroll
    for (int d = 0; d < 8; d++) {
      float za = qbcast(X[a & 1][d], a >> 1);
      U[0][d] += Ct0[a] * za;
      U[1][d] += Ct1[a] * za;
    }
#pragma unroll
  for (int r = 0; r < 2; r++)
#pragma unroll
    for (int c = 0; c < 8; c++) {
      float s = U[r][0] * DCT8[0][c];
#pragma unroll
      for (int d = 1; d < 8; d++) s += U[r][d] * DCT8[d][c];
      X[r][c] = s;
    }
}

// 16-point Walsh-Hadamard across lane bits 2..5, scale 1/4
__device__ __forceinline__ void had16r(float X[2][8], int lane) {
#pragma unroll
  for (int m = 4; m <= 32; m <<= 1) {
    bool hi = (lane & m) != 0;
#pragma unroll
    for (int r = 0; r < 2; r++)
#pragma unroll
      for (int d = 0; d < 8; d++) {
        float tv = sxor_f(X[r][d], m);
        X[r][d] = hi ? (tv - X[r][d]) : (X[r][d] + tv);
      }
  }
#pragma unroll
  for (int r = 0; r < 2; r++)
#pragma unroll
    for (int d = 0; d < 8; d++) X[r][d] *= 0.25f;
}

template <int WIEN>
__global__ __launch_bounds__(256, 2) void bm3d_pass(
    const int* __restrict__ img, const float* __restrict__ basic,
    const int* __restrict__ pvar,
    float* __restrict__ num, float* __restrict__ den) {
  __shared__ float ldsD[64], ldsDT[64];
  __shared__ __align__(16) float wdist[4][84];
  __shared__ int wsel[4][16];
  __shared__ float Rws[32 * 40];     // row box sums of squared tile
  __shared__ float S2[25 * 40];      // 8x8 box sums of squared tile
  __shared__ float bufA[32 * TS];    // tileS -> accN overlay
  __shared__ float bufB[32 * TS];    // tileN (step2) -> accD overlay

  int t = threadIdx.x;
  int brow = blockIdx.x / 24, bcb = blockIdx.x - brow * 24;
  int ri = brow * 4;
  int bim = ri - 12;       int bi = bim < 0 ? 0 : (bim > 352 ? 352 : bim);
  int ubm = 16 * bcb - 12; int ub = ubm < 0 ? 0 : (ubm > 352 ? 352 : ubm);

  if (t < 64) ldsD[t] = DCT8[t >> 3][t & 7];
  else if (t < 128) { int u = t - 64; ldsDT[u] = DCT8[u & 7][u >> 3]; }

  // ---- tile load: 32 rows x 11 float4 (44 cols), guard right edge ----
  for (int e4 = t; e4 < 352; e4 += 256) {
    int r = e4 / 11, c4 = (e4 - r * 11) << 2;
    int col = ub + c4;
    int gidx = (bi + r) * 384 + col;
    int o = r * TS + c4;
    if (col + 3 < 384) {
      int4 iv = *(const int4*)&img[gidx];
      float4 fv = make_float4((float)iv.x, (float)iv.y, (float)iv.z, (float)iv.w);
      if (WIEN) {
        *(float4*)&bufA[o] = *(const float4*)&basic[gidx];
        *(float4*)&bufB[o] = fv;
      } else {
        *(float4*)&bufA[o] = fv;
      }
    } else {
#pragma unroll
      for (int u = 0; u < 4; u++) {
        bool ok = (col + u) < 384;
        float fi = ok ? (float)img[gidx + u] : 0.f;
        if (WIEN) {
          bufA[o + u] = ok ? basic[gidx + u] : 0.f;
          bufB[o + u] = fi;
        } else {
          bufA[o + u] = fi;
        }
      }
    }
  }
  __syncthreads();

  // ---- box sums of squared match-source tile (separable) ----
  for (int e = t; e < 32 * 37; e += 256) {
    int r = e / 37, j = e - r * 37;
    const float* p = bufA + r * TS + j;
    float s = 0.f;
#pragma unroll
    for (int d = 0; d < 8; d++) { float v = p[d]; s += v * v; }
    Rws[r * 40 + j] = s;
  }
  __syncthreads();
  for (int e = t; e < 25 * 37; e += 256) {
    int i = e / 37, j = e - i * 37;
    float s = 0.f;
#pragma unroll
    for (int d = 0; d < 8; d++) s += Rws[(i + d) * 40 + j];
    S2[i * 40 + j] = s;
  }
  __syncthreads();

  float sigma2 = (float)pvar[0];
  int wv = t >> 6, lane = t & 63;
  int gc = bcb * 4 + wv;
  bool active = gc < 95;
  int rj = (active ? gc : 94) * 4;

  const float* tileS = bufA;                 // match source (basic in step2)
  const float* tileN = WIEN ? bufB : bufA;   // noisy pixels

  // ---- match: scr only (scc/srr from S2), candidates lane & 64+lane ----
  int cB = lane < 17 ? 64 + lane : 80;
  int aiA = iclip(ri + (lane / 9) * 3 - 12, 376) - bi;
  int ajA = iclip(rj + (lane % 9) * 3 - 12, 376) - ub;
  int aiB = iclip(ri + (cB / 9) * 3 - 12, 376) - bi;
  int ajB = iclip(rj + (cB % 9) * 3 - 12, 376) - ub;
  int roi = ri - bi, roj = rj - ub;

  float scrA = 0.f, scrB = 0.f;
#pragma unroll
  for (int i = 0; i < 8; i++) {
    float4 ra = *(const float4*)(tileS + (roi + i) * TS + roj);      // roj % 4 == 0
    float4 rb = *(const float4*)(tileS + (roi + i) * TS + roj + 4);
    float rv[8] = {ra.x, ra.y, ra.z, ra.w, rb.x, rb.y, rb.z, rb.w};
    const float* ap = tileS + (aiA + i) * TS + ajA;
    const float* bp = tileS + (aiB + i) * TS + ajB;
#pragma unroll
    for (int j = 0; j < 8; j++) {
      scrA += ap[j] * rv[j];
      scrB += bp[j] * rv[j];
    }
  }
  float srr = S2[roi * 40 + roj];
  float dA = fmaf(-2.f, scrA, S2[aiA * 40 + ajA]) + srr;
  float dB = lane < 17 ? fmaf(-2.f, scrB, S2[aiB * 40 + ajB]) + srr : FINF;

  // wave-local distance table (same-wave LDS RAW, no block barrier)
  wdist[wv][lane] = dA;
  if (lane < 17)      wdist[wv][64 + lane] = dB;
  else if (lane < 20) wdist[wv][64 + lane] = FINF;

  // ---- rank-count top-16 (lexicographic (d, idx) = lax.top_k order) ----
  int rA = 0, rB = 0;
  const float4* wp = (const float4*)&wdist[wv][0];
  int idxB = 64 + lane;
#pragma unroll 3
  for (int c4 = 0; c4 < 21; c4++) {
    float4 v = wp[c4];
    float ev[4] = {v.x, v.y, v.z, v.w};
#pragma unroll
    for (int u = 0; u < 4; u++) {
      int c2 = c4 * 4 + u;
      rA += (ev[u] < dA || (ev[u] == dA && c2 < lane)) ? 1 : 0;
      rB += (ev[u] < dB || (ev[u] == dB && c2 < idxB)) ? 1 : 0;
    }
  }
  if (rA < 16) wsel[wv][rA] = (aiA << 8) | ajA;
  if (lane < 17 && rB < 16) wsel[wv][rB] = (aiB << 8) | ajB;

  // ---- per-lane geometry + coefficients ----
  int k = lane >> 2, q = lane & 3;
  int sp = wsel[wv][k];
  int gi0 = (sp >> 8) + 2 * q, gj0 = sp & 255;

  float Ca0[8], Ca1[8];
  *(float4*)&Ca0[0] = *(const float4*)&ldsD[(2 * q) * 8];
  *(float4*)&Ca0[4] = *(const float4*)&ldsD[(2 * q) * 8 + 4];
  *(float4*)&Ca1[0] = *(const float4*)&ldsD[(2 * q + 1) * 8];
  *(float4*)&Ca1[4] = *(const float4*)&ldsD[(2 * q + 1) * 8 + 4];

  float X[2][8], U[2][8];
  float w;

  if (WIEN) {
    float Z[2][8];
#pragma unroll
    for (int r = 0; r < 2; r++)
#pragma unroll
      for (int c = 0; c < 8; c++) Z[r][c] = tileS[(gi0 + r) * TS + gj0 + c];
    fwd_rowcol(Z, U, Ca0, Ca1);
    had16r(Z, lane);                          // cb

#pragma unroll
    for (int r = 0; r < 2; r++)
#pragma unroll
      for (int c = 0; c < 8; c++) X[r][c] = tileN[(gi0 + r) * TS + gj0 + c];
    fwd_rowcol(X, U, Ca0, Ca1);
    had16r(X, lane);                          // cn

    float p = 0.f;
#pragma unroll
    for (int r = 0; r < 2; r++)
#pragma unroll
      for (int d = 0; d < 8; d++) {
        float cb = Z[r][d];
        float we = cb * cb / (cb * cb + sigma2);
        X[r][d] = we * X[r][d];
        p += we * we;
      }
#pragma unroll
    for (int m = 1; m <= 32; m <<= 1) p += sxor_f(p, m);
    w = 1.f / (sigma2 * fmaxf(p, 1e-8f));
  } else {
#pragma unroll
    for (int r = 0; r < 2; r++)
#pragma unroll
      for (int c = 0; c < 8; c++) X[r][c] = tileN[(gi0 + r) * TS + gj0 + c];
    fwd_rowcol(X, U, Ca0, Ca1);
    had16r(X, lane);

    float thr = 2.7f * sqrtf(sigma2);
    int cnt = 0;
#pragma unroll
    for (int r = 0; r < 2; r++)
#pragma unroll
      for (int d = 0; d < 8; d++) {
        bool keep = (fabsf(X[r][d]) > thr) || (lane == 0 && r == 0 && d == 0);
        cnt += (int)__popcll(__ballot(keep));
        if (!keep) X[r][d] = 0.f;
      }
    w = 1.f / (sigma2 * fmaxf((float)cnt, 1.f));
  }

  had16r(X, lane);
#pragma unroll
  for (int a = 0; a < 8; a++) {        // D^T rows for this lane's two b's
    Ca0[a] = ldsDT[(2 * q) * 8 + a];
    Ca1[a] = ldsDT[(2 * q + 1) * 8 + a];
  }
  inv_colrow(X, U, Ca0, Ca1);

  // ---- overlay: tiles dead, reuse as num/den accumulators ----
  __syncthreads();
  for (int e = t; e < 32 * TS; e += 256) { bufA[e] = 0.f; bufB[e] = 0.f; }
  __syncthreads();

  if (active) {
#pragma unroll
    for (int r = 0; r < 2; r++)
#pragma unroll
      for (int c = 0; c < 8; c++) {
        int off = (gi0 + r) * TS + gj0 + c;
        atomicAdd(&bufA[off], w * X[r][c]);
        atomicAdd(&bufB[off], w);
      }
  }
  __syncthreads();

  for (int e = t; e < 32 * TS; e += 256) {
    float dv = bufB[e];
    if (dv != 0.f) {
      int r = e / TS, c = e - r * TS;
      int gp = (bi + r) * 384 + ub + c;
      atomicAdd(&num[gp], bufA[e]);
      atomicAdd(&den[gp], dv);
    }
  }
}

__global__ void div_kernel(const float* __restrict__ num,
                           const float* __restrict__ den,
                           float* __restrict__ out, int npix) {
  int i = blockIdx.x * blockDim.x + threadIdx.x;
  if (i < npix) out[i] = num[i] / fmaxf(den[i], 1e-8f);
}

extern "C" void kernel_launch(void* const* d_in, const int* in_sizes, int n_in,
                              void* d_out, int out_size, void* d_ws, size_t ws_size,
                              hipStream_t stream) {
  const int* img  = (const int*)d_in[0];
  const int* pvar = (const int*)d_in[1];
  float* out = (float*)d_out;
  float* ws  = (float*)d_ws;

  const int NPIX = 384 * 384;
  float* num1  = ws + 0 * NPIX;
  float* den1  = ws + 1 * NPIX;
  float* basic = ws + 2 * NPIX;
  float* num2  = ws + 3 * NPIX;
  float* den2  = ws + 4 * NPIX;

  hipMemsetAsync(num1, 0, (size_t)2 * NPIX * sizeof(float), stream);
  hipMemsetAsync(num2, 0, (size_t)2 * NPIX * sizeof(float), stream);

  const int NBLK = 95 * 24;   // 95 rows x 24 col-blocks (4 groups each)
  bm3d_pass<0><<<NBLK, 256, 0, stream>>>(img, nullptr, pvar, num1, den1);
  div_kernel<<<(NPIX + 255) / 256, 256, 0, stream>>>(num1, den1, basic, NPIX);
  bm3d_pass<1><<<NBLK, 256, 0, stream>>>(img, basic, pvar, num2, den2);
  div_kernel<<<(NPIX + 255) / 256, 256, 0, stream>>>(num2, den2, out, NPIX);
}